// Round 6
// baseline (525.182 us; speedup 1.0000x reference)
//
#include <hip/hip_runtime.h>
#include <hip/hip_bf16.h>

typedef __hip_bfloat16 bf16;
typedef __attribute__((ext_vector_type(8))) short bf16x8;
typedef __attribute__((ext_vector_type(8))) unsigned short u16x8;
typedef __attribute__((ext_vector_type(4))) float f32x4;

#define NB 128      // batch
#define CIN 256     // DIM
#define NPIX 196    // 14*14
#define RESW 14
#define NH 8
#define KD 32
#define DV 128
#define DHID 1024
#define QKSCALE 0.17677669529663687f
#define QT 16       // queries per attention tile
#define NTILE 13    // ceil(196/16)
#define VSTRIDE 224 // padded pixel stride for Yv rows
#define ZPAD 232    // zb LDS m-stride (shorts): 464B, 16B-mult, distinct banks per nl
#define XSP 264     // Xs LDS c-stride (shorts): 528B, 16B-mult, 2-way banks
#define GROWS 208   // Gt padded rows per batch

__device__ __forceinline__ float bf2f(unsigned short u) {
  union { unsigned int i; float f; } x; x.i = ((unsigned int)u) << 16; return x.f;
}
__device__ __forceinline__ unsigned short f2bfs(float f) {  // RNE f32->bf16
  union { float f; unsigned int i; } u; u.f = f;
  unsigned int r = u.i + 0x7fffu + ((u.i >> 16) & 1u);
  return (unsigned short)(r >> 16);
}
__device__ __forceinline__ float gelu_exact(float x) {
  return x * 0.5f * (1.f + erff(x * 0.70710678118654752f));
}

// ---------------- K0: fold affines into bf16 transposed weights + mixed bias table --------
__global__ void k_fold(
    const float* wq, const float* bq, const float* sq, const float* tq,
    const float* wk, const float* bk, const float* sk, const float* tk,
    const float* wv, const float* bv, const float* sv, const float* tv,
    const float* wvl, const float* bvl_in, const float* svl, const float* tvl,
    const float* wp, const float* bp_in, const float* sp, const float* tp,
    const float* abias, const int* bidx, const float* w1, const float* b1,
    int noff,
    short* Wt, short* Wpt, float* bcat, float* bpf, float* Wvl, float* bvlf,
    float* AB1)
{
  int i = blockIdx.x * 256 + threadIdx.x;
  if (i < 393216) {           // Wt[o][c] bf16 (q 0..255, k 256..511, v 512..1535)
    int o = i >> 8, c = i & 255;
    float w, s;
    if (o < 256)      { w = wq[c * 256 + o];          s = sq[o]; }
    else if (o < 512) { w = wk[c * 256 + (o - 256)];  s = sk[o - 256]; }
    else              { w = wv[c * 1024 + (o - 512)]; s = sv[o - 512]; }
    Wt[i] = (short)f2bfs(w * s);
    return;
  }
  i -= 393216;
  if (i < 1536) {
    float b, s, t;
    if (i < 256)      { b = bq[i];        s = sq[i];        t = tq[i]; }
    else if (i < 512) { b = bk[i - 256];  s = sk[i - 256];  t = tk[i - 256]; }
    else              { b = bv[i - 512];  s = sv[i - 512];  t = tv[i - 512]; }
    bcat[i] = b * s + t;
    return;
  }
  i -= 1536;
  if (i < 262144) {           // Wpt[o][ch] bf16
    int o = i >> 10, ch = i & 1023;
    Wpt[i] = (short)f2bfs(wp[ch * 256 + o] * sp[o]);
    return;
  }
  i -= 262144;
  if (i < 256) { bpf[i] = bp_in[i] * sp[i] + tp[i]; return; }
  i -= 256;
  if (i < 9216) { int ch = i / 9; Wvl[i] = wvl[i] * svl[ch]; return; }
  i -= 9216;
  if (i < 1024) { bvlf[i] = bvl_in[i] * svl[i] + tvl[i]; return; }
  i -= 1024;
  if (i < NPIX * NPIX) {      // AB1[g][n][m] = b1[g] + sum_h w1[g][h]*abias[h][idx]
    int idx = bidx[i];
    float a[8];
#pragma unroll
    for (int h = 0; h < 8; ++h) a[h] = abias[h * noff + idx];
#pragma unroll
    for (int g = 0; g < 8; ++g) {
      float z = b1[g];
#pragma unroll
      for (int h = 0; h < 8; ++h) z += w1[g * 8 + h] * a[h];
      AB1[(size_t)g * NPIX * NPIX + i] = z;
    }
    return;
  }
}

// ---------------- K1: QKV projection via MFMA, X-transpose staged in LDS ----------------
// block = (b, n-half, o-group). Xs holds 112 rows of Xt[n][c]; o-group splits the
// 192 mm-units in two -> 512 blocks (2/CU).
__global__ __launch_bounds__(512) void k_qkv(
    const float* __restrict__ X, const short* __restrict__ Wt,
    const float* __restrict__ bcat, bf16* __restrict__ Yq,
    bf16* __restrict__ Yk, bf16* __restrict__ Yv)
{
  __shared__ short Xs[112 * XSP];
  int b = blockIdx.x >> 2, half = (blockIdx.x >> 1) & 1, og = blockIdx.x & 1;
  int t = threadIdx.x;
  const float* Xb = X + (size_t)b * CIN * NPIX;

  for (int i = t; i < 256 * 28; i += 512) {
    int c = i / 28, j = i % 28;
    int ng = half * 112 + 4 * j;
    int lr = 4 * j;
    if (ng + 3 < NPIX) {
      float4 xv = *(const float4*)(Xb + c * NPIX + ng);
      Xs[(lr + 0) * XSP + c] = (short)f2bfs(xv.x);
      Xs[(lr + 1) * XSP + c] = (short)f2bfs(xv.y);
      Xs[(lr + 2) * XSP + c] = (short)f2bfs(xv.z);
      Xs[(lr + 3) * XSP + c] = (short)f2bfs(xv.w);
    } else {
#pragma unroll
      for (int e = 0; e < 4; ++e) {
        float v = (ng + e < NPIX) ? Xb[c * NPIX + ng + e] : 0.f;
        Xs[(lr + e) * XSP + c] = (short)f2bfs(v);
      }
    }
  }
  __syncthreads();

  int w = t >> 6, lane = t & 63, nl = lane & 15, grp = lane >> 4;
  int NTH = half ? 6 : 7;
  int ntb = half * 7;

  for (int mm = og * 96 + w; mm < og * 96 + 96; mm += 8) {
    if (mm < 64) {
      int ot = mm >> 1, sub = mm & 1;
      int lt0 = sub * 4;
      int ltN = sub ? (NTH - 4) : 4;
      const short* arow = Wt + (size_t)(ot * 16 + nl) * CIN;
      f32x4 acc[4];
#pragma unroll
      for (int s = 0; s < 4; ++s) acc[s] = (f32x4){0.f, 0.f, 0.f, 0.f};
#pragma unroll
      for (int kk = 0; kk < 8; ++kk) {
        bf16x8 af = *(const bf16x8*)(arow + kk * 32 + grp * 8);
#pragma unroll
        for (int s = 0; s < 4; ++s) {
          if (s < ltN) {
            bf16x8 bfr = *(const bf16x8*)(Xs + ((lt0 + s) * 16 + nl) * XSP + kk * 32 + grp * 8);
            acc[s] = __builtin_amdgcn_mfma_f32_16x16x32_bf16(af, bfr, acc[s], 0, 0, 0);
          }
        }
      }
      int o0 = ot * 16 + grp * 4;
      float4 bb = *(const float4*)(bcat + o0);
      unsigned short* dst = (unsigned short*)((o0 < 256) ? Yq : Yk);
      int ob = o0 & 255;
#pragma unroll
      for (int s = 0; s < 4; ++s) {
        if (s < ltN) {
          int n = (ntb + lt0 + s) * 16 + nl;
          if (n < NPIX) {
            ushort4 pk;
            pk.x = f2bfs(acc[s][0] + bb.x); pk.y = f2bfs(acc[s][1] + bb.y);
            pk.z = f2bfs(acc[s][2] + bb.z); pk.w = f2bfs(acc[s][3] + bb.w);
            *(ushort4*)(dst + ((size_t)b * NPIX + n) * CIN + ob) = pk;
          }
        }
      }
    } else {
      int mm2 = mm - 64;
      int cht = mm2 >> 1, sub = mm2 & 1;
      int lt0 = sub * 4;
      int ltN = sub ? (NTH - 4) : 4;
      int ch = cht * 16 + nl;
      const short* brow = Wt + (size_t)(512 + ch) * CIN;
      f32x4 acc[4];
#pragma unroll
      for (int s = 0; s < 4; ++s) acc[s] = (f32x4){0.f, 0.f, 0.f, 0.f};
#pragma unroll
      for (int kk = 0; kk < 8; ++kk) {
        bf16x8 bfr = *(const bf16x8*)(brow + kk * 32 + grp * 8);
#pragma unroll
        for (int s = 0; s < 4; ++s) {
          if (s < ltN) {
            bf16x8 af = *(const bf16x8*)(Xs + ((lt0 + s) * 16 + nl) * XSP + kk * 32 + grp * 8);
            acc[s] = __builtin_amdgcn_mfma_f32_16x16x32_bf16(af, bfr, acc[s], 0, 0, 0);
          }
        }
      }
      float bb = bcat[512 + ch];
#pragma unroll
      for (int s = 0; s < 4; ++s) {
        if (s < ltN) {
          int m0 = (ntb + lt0 + s) * 16 + grp * 4;
          if (m0 + 3 < NPIX) {
            ushort4 pk;
            pk.x = f2bfs(acc[s][0] + bb); pk.y = f2bfs(acc[s][1] + bb);
            pk.z = f2bfs(acc[s][2] + bb); pk.w = f2bfs(acc[s][3] + bb);
            *(ushort4*)((unsigned short*)Yv + ((size_t)b * DHID + ch) * VSTRIDE + m0) = pk;
          }
        }
      }
    }
  }
}

// ---------------- K1b: depthwise 3x3 conv + bias -> Gt[b][n][ch] (bf16) ----------------
__global__ __launch_bounds__(512) void k_conv(
    const bf16* __restrict__ Yv, const float* __restrict__ Wvl,
    const float* __restrict__ bvlf, bf16* __restrict__ Gt)
{
  __shared__ short Vs[128 * ZPAD];
  int b = blockIdx.x >> 3, cg = blockIdx.x & 7;
  int t = threadIdx.x;
  const unsigned short* src = (const unsigned short*)Yv + ((size_t)b * DHID + cg * 128) * VSTRIDE;
  for (int i = t; i < 128 * 28; i += 512) {
    int ch = i / 28, j = i % 28;
    u16x8 v = *(const u16x8*)(src + ch * VSTRIDE + j * 8);
    *(u16x8*)(Vs + ch * ZPAD + j * 8) = v;
  }
  __syncthreads();

  int ch = t & 127, yg = t >> 7;
  int chg = cg * 128 + ch;
  float w9[9];
#pragma unroll
  for (int k = 0; k < 9; ++k) w9[k] = Wvl[chg * 9 + k];
  float bb = bvlf[chg];
  const short* row = Vs + ch * ZPAD;
  unsigned short* gbase = (unsigned short*)Gt + (size_t)b * GROWS * DHID + chg;

  int ylim = (yg == 3) ? 2 : 4;
  for (int yy = 0; yy < ylim; ++yy) {
    int y = yg * 4 + yy;
    float rw[3][14];
#pragma unroll
    for (int dy = 0; dy < 3; ++dy) {
      int ys = y + dy - 1;
      if (ys < 0 || ys >= RESW) {
#pragma unroll
        for (int x = 0; x < 14; ++x) rw[dy][x] = 0.f;
      } else {
#pragma unroll
        for (int x2 = 0; x2 < 7; ++x2) {
          unsigned int u = *(const unsigned int*)(row + ys * RESW + x2 * 2);
          rw[dy][x2 * 2]     = bf2f((unsigned short)(u & 0xffffu));
          rw[dy][x2 * 2 + 1] = bf2f((unsigned short)(u >> 16));
        }
      }
    }
#pragma unroll
    for (int x = 0; x < 14; ++x) {
      float a = bb;
#pragma unroll
      for (int dy = 0; dy < 3; ++dy)
#pragma unroll
        for (int dx = 0; dx < 3; ++dx) {
          int xx = x + dx - 1;
          if (xx >= 0 && xx < RESW) a += w9[dy * 3 + dx] * rw[dy][xx];
        }
      gbase[(size_t)(y * RESW + x) * DHID] = f2bfs(a);
    }
  }
}

// ---------------- K2: MFMA attention; th1 post-MFMA, th2 fused into softmax write -------
// Wave w owns m-tiles {w, w+8}/{5,13}/{6}/{7}. QK: 8 per-head K=32 MFMAs + fp32 th1 mix.
// Softmax 2-level. At write time each wave mixes all 8 output-heads A_j = b2+w2*P
// (f32) and stores A (bf16) in zb -> PV needs ONE b128 read per ks, zero build math.
__global__ __launch_bounds__(512) void k_attn(
    const bf16* __restrict__ Yq, const bf16* __restrict__ Yk,
    const bf16* __restrict__ Yv, const float* __restrict__ AB1,
    const float* __restrict__ w1, const float* __restrict__ w2,
    const float* __restrict__ b2, bf16* __restrict__ Gt)
{
  __shared__ short zb[NH][QT][ZPAD];   // mixed A (bf16), per out-head
  __shared__ float red[8][NH][16];     // cross-wave softmax partials
  int id = blockIdx.x;
  int swz = (id & 7) * (NB * NTILE / 8) + (id >> 3);  // XCD-chunked
  int b = swz / NTILE, tile = swz % NTILE;
  int n0 = tile * QT;
  int t = threadIdx.x;
  int w = t >> 6, lane = t & 63;
  int nl = lane & 15, grp = lane >> 4;
  int n = n0 + nl;
  int nA = (n < NPIX) ? n : (NPIX - 1);   // clamped (garbage cols discarded)

  int t0 = w;
  int t1 = (w < 5) ? (w + 8) : ((w == 5) ? 13 : -1);

  // ---- early prefetch: conv values (written by k_conv) — hides L2 latency under QK ----
  unsigned short* gp = (unsigned short*)Gt + ((size_t)b * GROWS + nA) * DHID + w * DV;
  ushort4 cvv[8];
#pragma unroll
  for (int dt = 0; dt < 8; ++dt) cvv[dt] = *(const ushort4*)(gp + dt * 16 + grp * 4);

  // ---- Q fragments per head (B-operand) ----
  const short* qrow = (const short*)Yq + ((size_t)b * NPIX + nA) * CIN;
  bf16x8 qf[8];
#pragma unroll
  for (int h = 0; h < 8; ++h) qf[h] = *(const bf16x8*)(qrow + h * 32 + grp * 8);

  const short* kbase = (const short*)Yk + (size_t)b * NPIX * CIN;
  const f32x4 NEG = (f32x4){-1e30f, -1e30f, -1e30f, -1e30f};
  f32x4 zm0[8], zm1[8];

#define DO_TILE(MT, ZM)                                                        \
  {                                                                            \
    int m0_ = (MT) * 16 + grp * 4;                                             \
    bool mv_ = (m0_ + 3) < NPIX;                                               \
    if ((MT) < 13) {                                                           \
      int mrow_ = (MT) * 16 + nl; if (mrow_ > NPIX - 1) mrow_ = NPIX - 1;      \
      const short* krow_ = kbase + (size_t)mrow_ * CIN + grp * 8;              \
      f32x4 zr_[8];                                                            \
      _Pragma("unroll")                                                        \
      for (int h = 0; h < 8; ++h) {                                            \
        bf16x8 kf_ = *(const bf16x8*)(krow_ + h * 32);                         \
        zr_[h] = __builtin_amdgcn_mfma_f32_16x16x32_bf16(                      \
            kf_, qf[h], (f32x4){0.f, 0.f, 0.f, 0.f}, 0, 0, 0);                 \
      }                                                                        \
      _Pragma("unroll")                                                        \
      for (int g = 0; g < 8; ++g) {                                            \
        if (mv_) {                                                             \
          f32x4 a_ = *(const f32x4*)(AB1 + ((size_t)g * NPIX + nA) * NPIX + m0_); \
          _Pragma("unroll")                                                    \
          for (int h = 0; h < 8; ++h) {                                        \
            float wgh_ = w1[g * 8 + h] * QKSCALE;                              \
            _Pragma("unroll")                                                  \
            for (int r = 0; r < 4; ++r) a_[r] += wgh_ * zr_[h][r];             \
          }                                                                    \
          ZM[g] = a_;                                                          \
        } else ZM[g] = NEG;                                                    \
      }                                                                        \
    } else {                                                                   \
      _Pragma("unroll")                                                        \
      for (int g = 0; g < 8; ++g) ZM[g] = NEG;                                 \
    }                                                                          \
  }

  DO_TILE(t0, zm0)
  if (t1 >= 0) { DO_TILE(t1, zm1) }
  else {
#pragma unroll
    for (int g = 0; g < 8; ++g) zm1[g] = NEG;
  }

  // ---- 2-level softmax: wave shuffle-reduce, then cross-wave via red[] ----
  float mg[8];
#pragma unroll
  for (int g = 0; g < 8; ++g) {
    float m_ = fmaxf(fmaxf(zm0[g][0], zm0[g][1]), fmaxf(zm0[g][2], zm0[g][3]));
    m_ = fmaxf(m_, fmaxf(fmaxf(zm1[g][0], zm1[g][1]), fmaxf(zm1[g][2], zm1[g][3])));
    m_ = fmaxf(m_, __shfl_xor(m_, 16));
    m_ = fmaxf(m_, __shfl_xor(m_, 32));
    mg[g] = m_;
  }
  if (lane < 16) {
#pragma unroll
    for (int g = 0; g < 8; ++g) red[w][g][nl] = mg[g];
  }
  __syncthreads();
  float fmx[8];
#pragma unroll
  for (int g = 0; g < 8; ++g) {
    float m_ = red[0][g][nl];
#pragma unroll
    for (int ww = 1; ww < 8; ++ww) m_ = fmaxf(m_, red[ww][g][nl]);
    fmx[g] = m_;
  }
  float sg[8];
#pragma unroll
  for (int g = 0; g < 8; ++g) {
    float s_ = 0.f;
#pragma unroll
    for (int r = 0; r < 4; ++r) { zm0[g][r] = __expf(zm0[g][r] - fmx[g]); s_ += zm0[g][r]; }
#pragma unroll
    for (int r = 0; r < 4; ++r) { zm1[g][r] = __expf(zm1[g][r] - fmx[g]); s_ += zm1[g][r]; }
    s_ += __shfl_xor(s_, 16);
    s_ += __shfl_xor(s_, 32);
    sg[g] = s_;
  }
  __syncthreads();   // all reads of red (max) complete
  if (lane < 16) {
#pragma unroll
    for (int g = 0; g < 8; ++g) red[w][g][nl] = sg[g];
  }
  __syncthreads();
  float inv[8];
#pragma unroll
  for (int g = 0; g < 8; ++g) {
    float s_ = red[0][g][nl];
#pragma unroll
    for (int ww = 1; ww < 8; ++ww) s_ += red[ww][g][nl];
    inv[g] = 1.f / s_;
  }

  // ---- normalized P in f32, then th2 mix -> A_j, write bf16 to zb ----
  float p0[8][4], p1[8][4];
#pragma unroll
  for (int g = 0; g < 8; ++g)
#pragma unroll
    for (int r = 0; r < 4; ++r) {
      p0[g][r] = zm0[g][r] * inv[g];
      p1[g][r] = zm1[g][r] * inv[g];
    }
  int m0a = t0 * 16 + grp * 4;
  bool v0 = m0a < NPIX;                         // whole quad valid (196%4==0)
  int m0b = (t1 >= 0) ? (t1 * 16 + grp * 4) : 0;
  bool v1 = (t1 >= 0) && (m0b < NPIX);
#pragma unroll
  for (int j = 0; j < 8; ++j) {
    float b2j = b2[j];
    float a0[4] = {b2j, b2j, b2j, b2j};
    float a1[4] = {b2j, b2j, b2j, b2j};
#pragma unroll
    for (int g = 0; g < 8; ++g) {
      float wv = w2[j * 8 + g];
#pragma unroll
      for (int r = 0; r < 4; ++r) {
        a0[r] += wv * p0[g][r];
        a1[r] += wv * p1[g][r];
      }
    }
    ushort4 pk0;
    if (v0) { pk0.x = f2bfs(a0[0]); pk0.y = f2bfs(a0[1]); pk0.z = f2bfs(a0[2]); pk0.w = f2bfs(a0[3]); }
    else    { pk0.x = 0; pk0.y = 0; pk0.z = 0; pk0.w = 0; }
    *(ushort4*)&zb[j][nl][m0a] = pk0;
    if (t1 >= 0) {
      ushort4 pk1;
      if (v1) { pk1.x = f2bfs(a1[0]); pk1.y = f2bfs(a1[1]); pk1.z = f2bfs(a1[2]); pk1.w = f2bfs(a1[3]); }
      else    { pk1.x = 0; pk1.y = 0; pk1.z = 0; pk1.w = 0; }
      *(ushort4*)&zb[j][nl][m0b] = pk1;
    }
  }
  __syncthreads();

  // ---- PV: O^T = V^T x A^T; wave = out-head w; Bf read directly (pre-mixed) ----
  f32x4 accO[8];
#pragma unroll
  for (int dt = 0; dt < 8; ++dt) accO[dt] = (f32x4){0.f, 0.f, 0.f, 0.f};
  const short* vbase = (const short*)Yv + ((size_t)b * DHID + w * DV) * VSTRIDE;
#pragma unroll
  for (int ks = 0; ks < 7; ++ks) {
    int moff = ks * 32 + grp * 8;
    bf16x8 Bf = *(const bf16x8*)&zb[w][nl][moff];
#pragma unroll
    for (int dt = 0; dt < 8; ++dt) {
      bf16x8 Af = *(const bf16x8*)(vbase + (size_t)(dt * 16 + nl) * VSTRIDE + moff);
      accO[dt] = __builtin_amdgcn_mfma_f32_16x16x32_bf16(Af, Bf, accO[dt], 0, 0, 0);
    }
  }

  // ---- epilogue: + conv (prefetched), exact gelu, write back Gt[n][ch] ----
  if (n < NPIX) {
#pragma unroll
    for (int dt = 0; dt < 8; ++dt) {
      ushort4 pk;
      float pre;
      pre = accO[dt][0] + bf2f(cvv[dt].x); pk.x = f2bfs(gelu_exact(pre));
      pre = accO[dt][1] + bf2f(cvv[dt].y); pk.y = f2bfs(gelu_exact(pre));
      pre = accO[dt][2] + bf2f(cvv[dt].z); pk.z = f2bfs(gelu_exact(pre));
      pre = accO[dt][3] + bf2f(cvv[dt].w); pk.w = f2bfs(gelu_exact(pre));
      *(ushort4*)(gp + dt * 16 + grp * 4) = pk;
    }
  }
}

// ---------------- K3: output projection via MFMA, 1 ot/wave, 2 blocks/CU ----------------
__global__ __launch_bounds__(256) void k_proj(
    const bf16* __restrict__ Gt, const short* __restrict__ Wpt,
    const float* __restrict__ bpf, float* __restrict__ out)
{
  int b = blockIdx.x >> 2, q = blockIdx.x & 3;
  int t = threadIdx.x, w = t >> 6, lane = t & 63, nl = lane & 15, grp = lane >> 4;
  int ot = q * 4 + w;
  const short* a0 = Wpt + (size_t)(ot * 16 + nl) * DHID + grp * 8;
  const short* bb = (const short*)Gt + (size_t)b * GROWS * DHID + (size_t)nl * DHID + grp * 8;
  f32x4 acc[13];
#pragma unroll
  for (int i = 0; i < 13; ++i) acc[i] = (f32x4){0.f, 0.f, 0.f, 0.f};
  for (int kk = 0; kk < 32; ++kk) {
    bf16x8 af = *(const bf16x8*)(a0 + kk * 32);
#pragma unroll
    for (int nt = 0; nt < 13; ++nt) {
      bf16x8 bfr = *(const bf16x8*)(bb + (size_t)(nt * 16) * DHID + kk * 32);
      acc[nt] = __builtin_amdgcn_mfma_f32_16x16x32_bf16(af, bfr, acc[nt], 0, 0, 0);
    }
  }
  int o0 = ot * 16 + grp * 4;
  float4 bv = *(const float4*)(bpf + o0);
  float ba[4] = {bv.x, bv.y, bv.z, bv.w};
#pragma unroll
  for (int nt = 0; nt < 13; ++nt) {
    int nn = nt * 16 + nl;
    if (nn < NPIX) {
#pragma unroll
      for (int r = 0; r < 4; ++r)
        out[((size_t)b * CIN + o0 + r) * NPIX + nn] = acc[nt][r] + ba[r];
    }
  }
}

extern "C" void kernel_launch(void* const* d_in, const int* in_sizes, int n_in,
                              void* d_out, int out_size, void* d_ws, size_t ws_size,
                              hipStream_t stream) {
  const float* X    = (const float*)d_in[0];
  const float* wq   = (const float*)d_in[1];
  const float* bq   = (const float*)d_in[2];
  const float* sq   = (const float*)d_in[3];
  const float* tq   = (const float*)d_in[4];
  const float* wk   = (const float*)d_in[5];
  const float* bk   = (const float*)d_in[6];
  const float* sk   = (const float*)d_in[7];
  const float* tk   = (const float*)d_in[8];
  const float* wv   = (const float*)d_in[9];
  const float* bv   = (const float*)d_in[10];
  const float* sv   = (const float*)d_in[11];
  const float* tv   = (const float*)d_in[12];
  const float* wvl  = (const float*)d_in[13];
  const float* bvl  = (const float*)d_in[14];
  const float* svl  = (const float*)d_in[15];
  const float* tvl  = (const float*)d_in[16];
  const float* w1   = (const float*)d_in[17];
  const float* b1   = (const float*)d_in[18];
  const float* w2   = (const float*)d_in[19];
  const float* b2   = (const float*)d_in[20];
  const float* wp   = (const float*)d_in[21];
  const float* bpp  = (const float*)d_in[22];
  const float* sp   = (const float*)d_in[23];
  const float* tp   = (const float*)d_in[24];
  const float* ab   = (const float*)d_in[25];
  const int*   bidx = (const int*)d_in[26];
  int noff = in_sizes[25] / NH;

  short* Wt   = (short*)d_ws;                    // 393216 shorts
  short* Wpt  = Wt + 393216;                     // 262144 shorts
  float* bcat = (float*)(Wpt + 262144);          // 1536
  float* bpf  = bcat + 1536;                     // 256
  float* Wvl  = bpf + 256;                       // 9216
  float* bvlf = Wvl + 9216;                      // 1024
  float* AB1  = bvlf + 1024;                     // 307328
  short* Yq   = (short*)(AB1 + 307328);          // 128*196*256
  short* Yk   = Yq + (size_t)NB * NPIX * CIN;
  short* Yv   = Yk + (size_t)NB * NPIX * CIN;    // 128*1024*224
  short* Gt   = Yv + (size_t)NB * DHID * VSTRIDE; // 128*208*1024

  k_fold<<<2758, 256, 0, stream>>>(wq, bq, sq, tq, wk, bk, sk, tk,
                                   wv, bv, sv, tv, wvl, bvl, svl, tvl,
                                   wp, bpp, sp, tp, ab, bidx, w1, b1, noff,
                                   Wt, Wpt, bcat, bpf, Wvl, bvlf, AB1);
  k_qkv<<<NB * 4, 512, 0, stream>>>(X, Wt, bcat, (bf16*)Yq, (bf16*)Yk, (bf16*)Yv);
  k_conv<<<NB * 8, 512, 0, stream>>>((const bf16*)Yv, Wvl, bvlf, (bf16*)Gt);
  k_attn<<<NB * NTILE, 512, 0, stream>>>((const bf16*)Yq, (const bf16*)Yk,
                                         (const bf16*)Yv, AB1, w1, w2, b2, (bf16*)Gt);
  k_proj<<<NB * 4, 256, 0, stream>>>((const bf16*)Gt, Wpt, bpf, (float*)d_out);
}

// Round 7
// 476.268 us; speedup vs baseline: 1.1027x; 1.1027x over previous
//
#include <hip/hip_runtime.h>
#include <hip/hip_bf16.h>

typedef __hip_bfloat16 bf16;
typedef __attribute__((ext_vector_type(8))) short bf16x8;
typedef __attribute__((ext_vector_type(8))) unsigned short u16x8;
typedef __attribute__((ext_vector_type(4))) float f32x4;

#define NB 128      // batch
#define CIN 256     // DIM
#define NPIX 196    // 14*14
#define RESW 14
#define NH 8
#define KD 32
#define DV 128
#define DHID 1024
#define QKSCALE 0.17677669529663687f
#define QT 16       // queries per attention tile
#define NTILE 13    // ceil(196/16)
#define VSTRIDE 224 // padded pixel stride for Yv rows
#define ZPAD 232    // zb LDS m-stride (shorts): 464B, 16B-mult
#define XSP 264     // Xs LDS c-stride (shorts): 528B, 16B-mult, 2-way banks
#define GROWS 208   // Gt padded rows per batch

__device__ __forceinline__ float bf2f(unsigned short u) {
  union { unsigned int i; float f; } x; x.i = ((unsigned int)u) << 16; return x.f;
}
__device__ __forceinline__ unsigned short f2bfs(float f) {  // RNE f32->bf16
  union { float f; unsigned int i; } u; u.f = f;
  unsigned int r = u.i + 0x7fffu + ((u.i >> 16) & 1u);
  return (unsigned short)(r >> 16);
}
__device__ __forceinline__ float gelu_exact(float x) {
  return x * 0.5f * (1.f + erff(x * 0.70710678118654752f));
}

// ---------------- K0: fold affines into bf16 transposed weights + mixed bias table --------
__global__ void k_fold(
    const float* wq, const float* bq, const float* sq, const float* tq,
    const float* wk, const float* bk, const float* sk, const float* tk,
    const float* wv, const float* bv, const float* sv, const float* tv,
    const float* wvl, const float* bvl_in, const float* svl, const float* tvl,
    const float* wp, const float* bp_in, const float* sp, const float* tp,
    const float* abias, const int* bidx, const float* w1, const float* b1,
    int noff,
    short* Wt, short* Wpt, float* bcat, float* bpf, float* Wvl, float* bvlf,
    float* AB1)
{
  int i = blockIdx.x * 256 + threadIdx.x;
  if (i < 393216) {           // Wt[o][c] bf16 (q 0..255, k 256..511, v 512..1535)
    int o = i >> 8, c = i & 255;
    float w, s;
    if (o < 256)      { w = wq[c * 256 + o];          s = sq[o]; }
    else if (o < 512) { w = wk[c * 256 + (o - 256)];  s = sk[o - 256]; }
    else              { w = wv[c * 1024 + (o - 512)]; s = sv[o - 512]; }
    Wt[i] = (short)f2bfs(w * s);
    return;
  }
  i -= 393216;
  if (i < 1536) {
    float b, s, t;
    if (i < 256)      { b = bq[i];        s = sq[i];        t = tq[i]; }
    else if (i < 512) { b = bk[i - 256];  s = sk[i - 256];  t = tk[i - 256]; }
    else              { b = bv[i - 512];  s = sv[i - 512];  t = tv[i - 512]; }
    bcat[i] = b * s + t;
    return;
  }
  i -= 1536;
  if (i < 262144) {           // Wpt[o][ch] bf16
    int o = i >> 10, ch = i & 1023;
    Wpt[i] = (short)f2bfs(wp[ch * 256 + o] * sp[o]);
    return;
  }
  i -= 262144;
  if (i < 256) { bpf[i] = bp_in[i] * sp[i] + tp[i]; return; }
  i -= 256;
  if (i < 9216) { int ch = i / 9; Wvl[i] = wvl[i] * svl[ch]; return; }
  i -= 9216;
  if (i < 1024) { bvlf[i] = bvl_in[i] * svl[i] + tvl[i]; return; }
  i -= 1024;
  if (i < NPIX * NPIX) {      // AB1[g][n][m] = b1[g] + sum_h w1[g][h]*abias[h][idx]
    int idx = bidx[i];
    float a[8];
#pragma unroll
    for (int h = 0; h < 8; ++h) a[h] = abias[h * noff + idx];
#pragma unroll
    for (int g = 0; g < 8; ++g) {
      float z = b1[g];
#pragma unroll
      for (int h = 0; h < 8; ++h) z += w1[g * 8 + h] * a[h];
      AB1[(size_t)g * NPIX * NPIX + i] = z;
    }
    return;
  }
}

// ---------------- K1: QKV projection via MFMA, X-transpose staged in LDS ----------------
__global__ __launch_bounds__(512) void k_qkv(
    const float* __restrict__ X, const short* __restrict__ Wt,
    const float* __restrict__ bcat, bf16* __restrict__ Yq,
    bf16* __restrict__ Yk, bf16* __restrict__ Yv)
{
  __shared__ short Xs[112 * XSP];
  int b = blockIdx.x >> 1, half = blockIdx.x & 1;
  int t = threadIdx.x;
  const float* Xb = X + (size_t)b * CIN * NPIX;

  for (int i = t; i < 256 * 28; i += 512) {
    int c = i / 28, j = i % 28;
    int ng = half * 112 + 4 * j;
    int lr = 4 * j;
    if (ng + 3 < NPIX) {
      float4 xv = *(const float4*)(Xb + c * NPIX + ng);
      Xs[(lr + 0) * XSP + c] = (short)f2bfs(xv.x);
      Xs[(lr + 1) * XSP + c] = (short)f2bfs(xv.y);
      Xs[(lr + 2) * XSP + c] = (short)f2bfs(xv.z);
      Xs[(lr + 3) * XSP + c] = (short)f2bfs(xv.w);
    } else {
#pragma unroll
      for (int e = 0; e < 4; ++e) {
        float v = (ng + e < NPIX) ? Xb[c * NPIX + ng + e] : 0.f;
        Xs[(lr + e) * XSP + c] = (short)f2bfs(v);
      }
    }
  }
  __syncthreads();

  int w = t >> 6, lane = t & 63, nl = lane & 15, grp = lane >> 4;
  int NTH = half ? 6 : 7;
  int ntb = half * 7;

  for (int mm = w; mm < 192; mm += 8) {
    if (mm < 64) {
      int ot = mm >> 1, sub = mm & 1;
      int lt0 = sub * 4;
      int ltN = sub ? (NTH - 4) : 4;
      const short* arow = Wt + (size_t)(ot * 16 + nl) * CIN;
      f32x4 acc[4];
#pragma unroll
      for (int s = 0; s < 4; ++s) acc[s] = (f32x4){0.f, 0.f, 0.f, 0.f};
#pragma unroll
      for (int kk = 0; kk < 8; ++kk) {
        bf16x8 af = *(const bf16x8*)(arow + kk * 32 + grp * 8);
#pragma unroll
        for (int s = 0; s < 4; ++s) {
          if (s < ltN) {
            bf16x8 bfr = *(const bf16x8*)(Xs + ((lt0 + s) * 16 + nl) * XSP + kk * 32 + grp * 8);
            acc[s] = __builtin_amdgcn_mfma_f32_16x16x32_bf16(af, bfr, acc[s], 0, 0, 0);
          }
        }
      }
      int o0 = ot * 16 + grp * 4;
      float4 bb = *(const float4*)(bcat + o0);
      unsigned short* dst = (unsigned short*)((o0 < 256) ? Yq : Yk);
      int ob = o0 & 255;
#pragma unroll
      for (int s = 0; s < 4; ++s) {
        if (s < ltN) {
          int n = (ntb + lt0 + s) * 16 + nl;
          if (n < NPIX) {
            ushort4 pk;
            pk.x = f2bfs(acc[s][0] + bb.x); pk.y = f2bfs(acc[s][1] + bb.y);
            pk.z = f2bfs(acc[s][2] + bb.z); pk.w = f2bfs(acc[s][3] + bb.w);
            *(ushort4*)(dst + ((size_t)b * NPIX + n) * CIN + ob) = pk;
          }
        }
      }
    } else {
      int mm2 = mm - 64;
      int cht = mm2 >> 1, sub = mm2 & 1;
      int lt0 = sub * 4;
      int ltN = sub ? (NTH - 4) : 4;
      int ch = cht * 16 + nl;
      const short* brow = Wt + (size_t)(512 + ch) * CIN;
      f32x4 acc[4];
#pragma unroll
      for (int s = 0; s < 4; ++s) acc[s] = (f32x4){0.f, 0.f, 0.f, 0.f};
#pragma unroll
      for (int kk = 0; kk < 8; ++kk) {
        bf16x8 bfr = *(const bf16x8*)(brow + kk * 32 + grp * 8);
#pragma unroll
        for (int s = 0; s < 4; ++s) {
          if (s < ltN) {
            bf16x8 af = *(const bf16x8*)(Xs + ((lt0 + s) * 16 + nl) * XSP + kk * 32 + grp * 8);
            acc[s] = __builtin_amdgcn_mfma_f32_16x16x32_bf16(af, bfr, acc[s], 0, 0, 0);
          }
        }
      }
      float bb = bcat[512 + ch];
#pragma unroll
      for (int s = 0; s < 4; ++s) {
        if (s < ltN) {
          int m0 = (ntb + lt0 + s) * 16 + grp * 4;
          if (m0 + 3 < NPIX) {
            ushort4 pk;
            pk.x = f2bfs(acc[s][0] + bb); pk.y = f2bfs(acc[s][1] + bb);
            pk.z = f2bfs(acc[s][2] + bb); pk.w = f2bfs(acc[s][3] + bb);
            *(ushort4*)((unsigned short*)Yv + ((size_t)b * DHID + ch) * VSTRIDE + m0) = pk;
          }
        }
      }
    }
  }
}

// ---------------- K1b: depthwise 3x3 conv + bias -> Gt[b][n][ch] (bf16) ----------------
__global__ __launch_bounds__(512) void k_conv(
    const bf16* __restrict__ Yv, const float* __restrict__ Wvl,
    const float* __restrict__ bvlf, bf16* __restrict__ Gt)
{
  __shared__ short Vs[128 * ZPAD];
  int b = blockIdx.x >> 3, cg = blockIdx.x & 7;
  int t = threadIdx.x;
  const unsigned short* src = (const unsigned short*)Yv + ((size_t)b * DHID + cg * 128) * VSTRIDE;
  for (int i = t; i < 128 * 28; i += 512) {
    int ch = i / 28, j = i % 28;
    u16x8 v = *(const u16x8*)(src + ch * VSTRIDE + j * 8);
    *(u16x8*)(Vs + ch * ZPAD + j * 8) = v;
  }
  __syncthreads();

  int ch = t & 127, yg = t >> 7;
  int chg = cg * 128 + ch;
  float w9[9];
#pragma unroll
  for (int k = 0; k < 9; ++k) w9[k] = Wvl[chg * 9 + k];
  float bb = bvlf[chg];
  const short* row = Vs + ch * ZPAD;
  unsigned short* gbase = (unsigned short*)Gt + (size_t)b * GROWS * DHID + chg;

  int ylim = (yg == 3) ? 2 : 4;
  for (int yy = 0; yy < ylim; ++yy) {
    int y = yg * 4 + yy;
    float rw[3][14];
#pragma unroll
    for (int dy = 0; dy < 3; ++dy) {
      int ys = y + dy - 1;
      if (ys < 0 || ys >= RESW) {
#pragma unroll
        for (int x = 0; x < 14; ++x) rw[dy][x] = 0.f;
      } else {
#pragma unroll
        for (int x2 = 0; x2 < 7; ++x2) {
          unsigned int u = *(const unsigned int*)(row + ys * RESW + x2 * 2);
          rw[dy][x2 * 2]     = bf2f((unsigned short)(u & 0xffffu));
          rw[dy][x2 * 2 + 1] = bf2f((unsigned short)(u >> 16));
        }
      }
    }
#pragma unroll
    for (int x = 0; x < 14; ++x) {
      float a = bb;
#pragma unroll
      for (int dy = 0; dy < 3; ++dy)
#pragma unroll
        for (int dx = 0; dx < 3; ++dx) {
          int xx = x + dx - 1;
          if (xx >= 0 && xx < RESW) a += w9[dy * 3 + dx] * rw[dy][xx];
        }
      gbase[(size_t)(y * RESW + x) * DHID] = f2bfs(a);
    }
  }
}

// ---------------- K2: MFMA attention; th1 post-MFMA, th2 fused into softmax write -------
// Wave w owns m-tiles {w, w+8}/{5,13}/{6}/{7}. PV reads pre-mixed A from zb (1 b128/ks)
// with one-ks-ahead V register prefetch; conv prefetch placed LATE (R5's 91MB-FETCH cfg).
__global__ __launch_bounds__(512, 4) void k_attn(
    const bf16* __restrict__ Yq, const bf16* __restrict__ Yk,
    const bf16* __restrict__ Yv, const float* __restrict__ AB1,
    const float* __restrict__ w1, const float* __restrict__ w2,
    const float* __restrict__ b2, bf16* __restrict__ Gt)
{
  __shared__ short zb[NH][QT][ZPAD];   // mixed A (bf16), per out-head
  __shared__ float red[8][NH][16];     // cross-wave softmax partials
  int id = blockIdx.x;
  int swz = (id & 7) * (NB * NTILE / 8) + (id >> 3);  // XCD-chunked
  int b = swz / NTILE, tile = swz % NTILE;
  int n0 = tile * QT;
  int t = threadIdx.x;
  int w = t >> 6, lane = t & 63;
  int nl = lane & 15, grp = lane >> 4;
  int n = n0 + nl;
  int nA = (n < NPIX) ? n : (NPIX - 1);   // clamped (garbage cols discarded)

  int t0 = w;
  int t1 = (w < 5) ? (w + 8) : ((w == 5) ? 13 : -1);

  // ---- Q fragments per head (B-operand) ----
  const short* qrow = (const short*)Yq + ((size_t)b * NPIX + nA) * CIN;
  bf16x8 qf[8];
#pragma unroll
  for (int h = 0; h < 8; ++h) qf[h] = *(const bf16x8*)(qrow + h * 32 + grp * 8);

  const short* kbase = (const short*)Yk + (size_t)b * NPIX * CIN;
  const f32x4 NEG = (f32x4){-1e30f, -1e30f, -1e30f, -1e30f};
  f32x4 zm0[8], zm1[8];

#define DO_TILE(MT, ZM)                                                        \
  {                                                                            \
    int m0_ = (MT) * 16 + grp * 4;                                             \
    bool mv_ = (m0_ + 3) < NPIX;                                               \
    if ((MT) < 13) {                                                           \
      int mrow_ = (MT) * 16 + nl; if (mrow_ > NPIX - 1) mrow_ = NPIX - 1;      \
      const short* krow_ = kbase + (size_t)mrow_ * CIN + grp * 8;              \
      f32x4 zr_[8];                                                            \
      _Pragma("unroll")                                                        \
      for (int h = 0; h < 8; ++h) {                                            \
        bf16x8 kf_ = *(const bf16x8*)(krow_ + h * 32);                         \
        zr_[h] = __builtin_amdgcn_mfma_f32_16x16x32_bf16(                      \
            kf_, qf[h], (f32x4){0.f, 0.f, 0.f, 0.f}, 0, 0, 0);                 \
      }                                                                        \
      _Pragma("unroll")                                                        \
      for (int g = 0; g < 8; ++g) {                                            \
        if (mv_) {                                                             \
          f32x4 a_ = *(const f32x4*)(AB1 + ((size_t)g * NPIX + nA) * NPIX + m0_); \
          _Pragma("unroll")                                                    \
          for (int h = 0; h < 8; ++h) {                                        \
            float wgh_ = w1[g * 8 + h] * QKSCALE;                              \
            _Pragma("unroll")                                                  \
            for (int r = 0; r < 4; ++r) a_[r] += wgh_ * zr_[h][r];             \
          }                                                                    \
          ZM[g] = a_;                                                          \
        } else ZM[g] = NEG;                                                    \
      }                                                                        \
    } else {                                                                   \
      _Pragma("unroll")                                                        \
      for (int g = 0; g < 8; ++g) ZM[g] = NEG;                                 \
    }                                                                          \
  }

  DO_TILE(t0, zm0)
  if (t1 >= 0) { DO_TILE(t1, zm1) }
  else {
#pragma unroll
    for (int g = 0; g < 8; ++g) zm1[g] = NEG;
  }

  // ---- 2-level softmax: wave shuffle-reduce, then cross-wave via red[] ----
  float mg[8];
#pragma unroll
  for (int g = 0; g < 8; ++g) {
    float m_ = fmaxf(fmaxf(zm0[g][0], zm0[g][1]), fmaxf(zm0[g][2], zm0[g][3]));
    m_ = fmaxf(m_, fmaxf(fmaxf(zm1[g][0], zm1[g][1]), fmaxf(zm1[g][2], zm1[g][3])));
    m_ = fmaxf(m_, __shfl_xor(m_, 16));
    m_ = fmaxf(m_, __shfl_xor(m_, 32));
    mg[g] = m_;
  }
  if (lane < 16) {
#pragma unroll
    for (int g = 0; g < 8; ++g) red[w][g][nl] = mg[g];
  }
  __syncthreads();
  float fmx[8];
#pragma unroll
  for (int g = 0; g < 8; ++g) {
    float m_ = red[0][g][nl];
#pragma unroll
    for (int ww = 1; ww < 8; ++ww) m_ = fmaxf(m_, red[ww][g][nl]);
    fmx[g] = m_;
  }
  float sg[8];
#pragma unroll
  for (int g = 0; g < 8; ++g) {
    float s_ = 0.f;
#pragma unroll
    for (int r = 0; r < 4; ++r) { zm0[g][r] = __expf(zm0[g][r] - fmx[g]); s_ += zm0[g][r]; }
#pragma unroll
    for (int r = 0; r < 4; ++r) { zm1[g][r] = __expf(zm1[g][r] - fmx[g]); s_ += zm1[g][r]; }
    s_ += __shfl_xor(s_, 16);
    s_ += __shfl_xor(s_, 32);
    sg[g] = s_;
  }
  __syncthreads();   // all reads of red (max) complete
  if (lane < 16) {
#pragma unroll
    for (int g = 0; g < 8; ++g) red[w][g][nl] = sg[g];
  }
  __syncthreads();
  float inv[8];
#pragma unroll
  for (int g = 0; g < 8; ++g) {
    float s_ = red[0][g][nl];
#pragma unroll
    for (int ww = 1; ww < 8; ++ww) s_ += red[ww][g][nl];
    inv[g] = 1.f / s_;
  }

  // ---- normalized P in f32, then th2 mix -> A_j, write bf16 to zb ----
  float p0[8][4], p1[8][4];
#pragma unroll
  for (int g = 0; g < 8; ++g)
#pragma unroll
    for (int r = 0; r < 4; ++r) {
      p0[g][r] = zm0[g][r] * inv[g];
      p1[g][r] = zm1[g][r] * inv[g];
    }
  int m0a = t0 * 16 + grp * 4;
  bool v0 = m0a < NPIX;
  int m0b = (t1 >= 0) ? (t1 * 16 + grp * 4) : 0;
  bool v1 = (t1 >= 0) && (m0b < NPIX);
#pragma unroll
  for (int j = 0; j < 8; ++j) {
    float b2j = b2[j];
    float a0[4] = {b2j, b2j, b2j, b2j};
    float a1[4] = {b2j, b2j, b2j, b2j};
#pragma unroll
    for (int g = 0; g < 8; ++g) {
      float wv = w2[j * 8 + g];
#pragma unroll
      for (int r = 0; r < 4; ++r) {
        a0[r] += wv * p0[g][r];
        a1[r] += wv * p1[g][r];
      }
    }
    ushort4 pk0;
    if (v0) { pk0.x = f2bfs(a0[0]); pk0.y = f2bfs(a0[1]); pk0.z = f2bfs(a0[2]); pk0.w = f2bfs(a0[3]); }
    else    { pk0.x = 0; pk0.y = 0; pk0.z = 0; pk0.w = 0; }
    *(ushort4*)&zb[j][nl][m0a] = pk0;
    if (t1 >= 0) {
      ushort4 pk1;
      if (v1) { pk1.x = f2bfs(a1[0]); pk1.y = f2bfs(a1[1]); pk1.z = f2bfs(a1[2]); pk1.w = f2bfs(a1[3]); }
      else    { pk1.x = 0; pk1.y = 0; pk1.z = 0; pk1.w = 0; }
      *(ushort4*)&zb[j][nl][m0b] = pk1;
    }
  }

  // ---- LATE conv prefetch (R5 placement: after zb writes, before barrier) ----
  unsigned short* gp = (unsigned short*)Gt + ((size_t)b * GROWS + nA) * DHID + w * DV;
  ushort4 cvv[8];
#pragma unroll
  for (int dt = 0; dt < 8; ++dt) cvv[dt] = *(const ushort4*)(gp + dt * 16 + grp * 4);
  __syncthreads();

  // ---- PV: O^T = V^T x A^T; wave = out-head w; one-ks-ahead V register prefetch ----
  f32x4 accO[8];
#pragma unroll
  for (int dt = 0; dt < 8; ++dt) accO[dt] = (f32x4){0.f, 0.f, 0.f, 0.f};
  const short* vbase = (const short*)Yv + ((size_t)b * DHID + w * DV) * VSTRIDE;
  bf16x8 Afq[2][8];
#pragma unroll
  for (int dt = 0; dt < 8; ++dt)
    Afq[0][dt] = *(const bf16x8*)(vbase + (size_t)(dt * 16 + nl) * VSTRIDE + grp * 8);
#pragma unroll
  for (int ks = 0; ks < 7; ++ks) {
    int moff = ks * 32 + grp * 8;
    if (ks < 6) {
      int mo2 = moff + 32;
#pragma unroll
      for (int dt = 0; dt < 8; ++dt)
        Afq[(ks & 1) ^ 1][dt] = *(const bf16x8*)(vbase + (size_t)(dt * 16 + nl) * VSTRIDE + mo2);
    }
    bf16x8 Bf = *(const bf16x8*)&zb[w][nl][moff];
#pragma unroll
    for (int dt = 0; dt < 8; ++dt)
      accO[dt] = __builtin_amdgcn_mfma_f32_16x16x32_bf16(Afq[ks & 1][dt], Bf, accO[dt], 0, 0, 0);
  }

  // ---- epilogue: + conv (prefetched), exact gelu, write back Gt[n][ch] ----
  if (n < NPIX) {
#pragma unroll
    for (int dt = 0; dt < 8; ++dt) {
      ushort4 pk;
      float pre;
      pre = accO[dt][0] + bf2f(cvv[dt].x); pk.x = f2bfs(gelu_exact(pre));
      pre = accO[dt][1] + bf2f(cvv[dt].y); pk.y = f2bfs(gelu_exact(pre));
      pre = accO[dt][2] + bf2f(cvv[dt].z); pk.z = f2bfs(gelu_exact(pre));
      pre = accO[dt][3] + bf2f(cvv[dt].w); pk.w = f2bfs(gelu_exact(pre));
      *(ushort4*)(gp + dt * 16 + grp * 4) = pk;
    }
  }
}

// ---------------- K3: output projection via MFMA, 2-ot register blocking (R5 cfg) -------
__global__ __launch_bounds__(256) void k_proj(
    const bf16* __restrict__ Gt, const short* __restrict__ Wpt,
    const float* __restrict__ bpf, float* __restrict__ out)
{
  int b = blockIdx.x >> 1, half = blockIdx.x & 1;
  int t = threadIdx.x, w = t >> 6, lane = t & 63, nl = lane & 15, grp = lane >> 4;
  int ot0 = half * 8 + w;       // w in 0..3
  int ot1 = ot0 + 4;
  const short* a0 = Wpt + (size_t)(ot0 * 16 + nl) * DHID + grp * 8;
  const short* a1 = Wpt + (size_t)(ot1 * 16 + nl) * DHID + grp * 8;
  const short* bb = (const short*)Gt + (size_t)b * GROWS * DHID + (size_t)nl * DHID + grp * 8;
  f32x4 acc0[13], acc1[13];
#pragma unroll
  for (int i = 0; i < 13; ++i) {
    acc0[i] = (f32x4){0.f, 0.f, 0.f, 0.f};
    acc1[i] = (f32x4){0.f, 0.f, 0.f, 0.f};
  }
  for (int kk = 0; kk < 32; ++kk) {
    bf16x8 af0 = *(const bf16x8*)(a0 + kk * 32);
    bf16x8 af1 = *(const bf16x8*)(a1 + kk * 32);
#pragma unroll
    for (int nt = 0; nt < 13; ++nt) {
      bf16x8 bfr = *(const bf16x8*)(bb + (size_t)(nt * 16) * DHID + kk * 32);
      acc0[nt] = __builtin_amdgcn_mfma_f32_16x16x32_bf16(af0, bfr, acc0[nt], 0, 0, 0);
      acc1[nt] = __builtin_amdgcn_mfma_f32_16x16x32_bf16(af1, bfr, acc1[nt], 0, 0, 0);
    }
  }
  int o0 = ot0 * 16 + grp * 4;
  int o1 = ot1 * 16 + grp * 4;
  float4 b0 = *(const float4*)(bpf + o0);
  float4 b1v = *(const float4*)(bpf + o1);
  float b0a[4] = {b0.x, b0.y, b0.z, b0.w};
  float b1a[4] = {b1v.x, b1v.y, b1v.z, b1v.w};
#pragma unroll
  for (int nt = 0; nt < 13; ++nt) {
    int nn = nt * 16 + nl;
    if (nn < NPIX) {
#pragma unroll
      for (int r = 0; r < 4; ++r) {
        out[((size_t)b * CIN + o0 + r) * NPIX + nn] = acc0[nt][r] + b0a[r];
        out[((size_t)b * CIN + o1 + r) * NPIX + nn] = acc1[nt][r] + b1a[r];
      }
    }
  }
}

extern "C" void kernel_launch(void* const* d_in, const int* in_sizes, int n_in,
                              void* d_out, int out_size, void* d_ws, size_t ws_size,
                              hipStream_t stream) {
  const float* X    = (const float*)d_in[0];
  const float* wq   = (const float*)d_in[1];
  const float* bq   = (const float*)d_in[2];
  const float* sq   = (const float*)d_in[3];
  const float* tq   = (const float*)d_in[4];
  const float* wk   = (const float*)d_in[5];
  const float* bk   = (const float*)d_in[6];
  const float* sk   = (const float*)d_in[7];
  const float* tk   = (const float*)d_in[8];
  const float* wv   = (const float*)d_in[9];
  const float* bv   = (const float*)d_in[10];
  const float* sv   = (const float*)d_in[11];
  const float* tv   = (const float*)d_in[12];
  const float* wvl  = (const float*)d_in[13];
  const float* bvl  = (const float*)d_in[14];
  const float* svl  = (const float*)d_in[15];
  const float* tvl  = (const float*)d_in[16];
  const float* w1   = (const float*)d_in[17];
  const float* b1   = (const float*)d_in[18];
  const float* w2   = (const float*)d_in[19];
  const float* b2   = (const float*)d_in[20];
  const float* wp   = (const float*)d_in[21];
  const float* bpp  = (const float*)d_in[22];
  const float* sp   = (const float*)d_in[23];
  const float* tp   = (const float*)d_in[24];
  const float* ab   = (const float*)d_in[25];
  const int*   bidx = (const int*)d_in[26];
  int noff = in_sizes[25] / NH;

  short* Wt   = (short*)d_ws;                    // 393216 shorts
  short* Wpt  = Wt + 393216;                     // 262144 shorts
  float* bcat = (float*)(Wpt + 262144);          // 1536
  float* bpf  = bcat + 1536;                     // 256
  float* Wvl  = bpf + 256;                       // 9216
  float* bvlf = Wvl + 9216;                      // 1024
  float* AB1  = bvlf + 1024;                     // 307328
  short* Yq   = (short*)(AB1 + 307328);          // 128*196*256
  short* Yk   = Yq + (size_t)NB * NPIX * CIN;
  short* Yv   = Yk + (size_t)NB * NPIX * CIN;    // 128*1024*224
  short* Gt   = Yv + (size_t)NB * DHID * VSTRIDE; // 128*208*1024

  k_fold<<<2758, 256, 0, stream>>>(wq, bq, sq, tq, wk, bk, sk, tk,
                                   wv, bv, sv, tv, wvl, bvl, svl, tvl,
                                   wp, bpp, sp, tp, ab, bidx, w1, b1, noff,
                                   Wt, Wpt, bcat, bpf, Wvl, bvlf, AB1);
  k_qkv<<<NB * 2, 512, 0, stream>>>(X, Wt, bcat, (bf16*)Yq, (bf16*)Yk, (bf16*)Yv);
  k_conv<<<NB * 8, 512, 0, stream>>>((const bf16*)Yv, Wvl, bvlf, (bf16*)Gt);
  k_attn<<<NB * NTILE, 512, 0, stream>>>((const bf16*)Yq, (const bf16*)Yk,
                                         (const bf16*)Yv, AB1, w1, w2, b2, (bf16*)Gt);
  k_proj<<<NB * 2, 256, 0, stream>>>((const bf16*)Gt, Wpt, bpf, (float*)d_out);
}